// Round 6
// baseline (118.933 us; speedup 1.0000x reference)
//
#include <hip/hip_runtime.h>
#include <hip/hip_fp16.h>

// Problem constants (match reference)
#define BB 8
#define CC 128
#define HH 112
#define WW 112
#define NTH 448            // 16 row-groups x 28 col-groups = 7 FULL waves
#define RG 7               // output rows per thread (16*7 = 112 = full plane)

// LUT depthwise 3x3, stride 1, pad 1:
//   t1 = clip(round(w*1000)), t2 = clip(round(x_pad)), both [-255,255]
//   out = sum_taps sign(t1,t2)*lut[|t1|,|t2|] / 1000 (sign=+1 iff strictly same sign)
//
// R6 (latency-bound per R5 post-mortem: 3.5 waves/SIMD + half-empty wave):
//  - 448 threads = 7 full waves; 4 outputs/thread; grid 1024 -> 4 blocks/CU
//    = 7 waves/SIMD (2x residency, 0% dead lanes).
//  - half4 tables: T[r][idx] = (half2(k0,k1), half2(k2,0)). One ds_read_b64
//    per pixel per kernel row (4.5 gather-instrs/output, was 6.4).
//  - Rolling 3-row offset buffer (each input row quantized once per thread);
//    pre-scaled byte offsets (idx<<3); fma_mix accumulate with /1000 folded.
__global__ __launch_bounds__(NTH, 7)
void approx_dconv_kernel(const float* __restrict__ x,
                         const float* __restrict__ w,
                         const float* __restrict__ lut,
                         float* __restrict__ out) {
    __shared__ uint2 T[3][512];     // lo = half2(k0,k1), hi = half2(k2, 0)

    const int tid = threadIdx.x;
    const int bc  = blockIdx.x;     // b*CC + c
    const int c   = bc % CC;

    // ---- 1) build signed per-tap tables (mirror fill, b64 writes) --------
    const float* wc = w + c * 9;
    if (tid < 256) {
        const int i = tid;          // i == |t2|
        #pragma unroll
        for (int r = 0; r < 3; ++r) {
            float pv[3], nv[3];
            #pragma unroll
            for (int k = 0; k < 3; ++k) {
                float t1 = rintf(wc[r * 3 + k] * 1000.0f);
                t1 = fminf(fmaxf(t1, -255.0f), 255.0f);
                const int  i1 = (int)fabsf(t1);
                const float v = lut[i1 * 256 + i];     // coalesced row read
                pv[k] = ((t1 > 0.0f) && i > 0) ? v : -v;   // t2 = +i
                nv[k] = ((t1 < 0.0f) && i > 0) ? v : -v;   // t2 = -i
            }
            __half2 pa = __halves2half2(__float2half_rn(pv[0]), __float2half_rn(pv[1]));
            __half2 pb = __halves2half2(__float2half_rn(pv[2]), __float2half_rn(0.0f));
            __half2 na = __halves2half2(__float2half_rn(nv[0]), __float2half_rn(nv[1]));
            __half2 nb = __halves2half2(__float2half_rn(nv[2]), __float2half_rn(0.0f));
            uint2 ep, en;
            ep.x = *(unsigned*)&pa; ep.y = *(unsigned*)&pb;
            en.x = *(unsigned*)&na; en.y = *(unsigned*)&nb;
            T[r][255 + i] = ep;
            T[r][255 - i] = en;
        }
    }
    __syncthreads();

    // ---- 2) compute: rolling 3-row offsets, 4 outputs per row-iter -------
    const int rg = tid / 28;                     // 0..15
    const int cg = tid % 28;                     // 0..27
    const int y0 = rg * RG;
    const int c0 = cg * 4;
    const float* xp = x + (size_t)bc * (HH * WW);
    float* op = out + (size_t)bc * (HH * WW);

    int off[3][6];                               // byte offsets, pixels c0-1 .. c0+4

    auto loadq = [&](int py, int* o) {
        if (py >= 0 && py < HH) {
            const float* rp = xp + py * WW + c0;
            float p[6];
            p[0] = (cg > 0) ? rp[-1] : 0.0f;     // left halo / zero pad
            const float4 A = *(const float4*)rp;
            p[1] = A.x; p[2] = A.y; p[3] = A.z; p[4] = A.w;
            p[5] = (cg < 27) ? rp[4] : 0.0f;     // right halo / zero pad
            #pragma unroll
            for (int j = 0; j < 6; ++j) {
                const float f = __builtin_amdgcn_fmed3f(rintf(p[j]), -255.0f, 255.0f);
                o[j] = (((int)f) + 255) << 3;
            }
        } else {
            #pragma unroll
            for (int j = 0; j < 6; ++j) o[j] = 255 << 3;
        }
    };

    loadq(y0 - 1, off[0]);
    loadq(y0,     off[1]);
    const float cmul = 0.001f;

    #pragma unroll
    for (int y = 0; y < RG; ++y) {
        loadq(y0 + y + 1, off[(y + 2) % 3]);     // quantize new input row once
        float acc[4];
        #pragma unroll
        for (int j = 0; j < 4; ++j) acc[j] = 0.0f;
        #pragma unroll
        for (int r = 0; r < 3; ++r) {            // kernel row r: input row y0+y+r-1
            const int* o = off[(y + r) % 3];
            const char* Tb = (const char*)&T[r][0];
            uint2 G[6];
            #pragma unroll
            for (int j = 0; j < 6; ++j) G[j] = *(const uint2*)(Tb + o[j]);
            #pragma unroll
            for (int j = 0; j < 4; ++j) {
                const __half2 ab = *(const __half2*)&G[j].x;       // (k0,k1) @ px j-1
                const __half2 bb = *(const __half2*)&G[j + 1].x;   // (k0,k1) @ px j
                const __half2 cb = *(const __half2*)&G[j + 2].y;   // (k2, 0) @ px j+1
                acc[j] = fmaf(__low2float(ab),  cmul, acc[j]);     // k0 @ px c-1
                acc[j] = fmaf(__high2float(bb), cmul, acc[j]);     // k1 @ px c
                acc[j] = fmaf(__low2float(cb),  cmul, acc[j]);     // k2 @ px c+1
            }
        }
        float* od = op + (y0 + y) * WW + c0;
        *(float4*)od = make_float4(acc[0], acc[1], acc[2], acc[3]);
    }
}

extern "C" void kernel_launch(void* const* d_in, const int* in_sizes, int n_in,
                              void* d_out, int out_size, void* d_ws, size_t ws_size,
                              hipStream_t stream) {
    const float* x   = (const float*)d_in[0];
    const float* w   = (const float*)d_in[1];
    const float* lut = (const float*)d_in[2];
    float* out = (float*)d_out;
    (void)in_sizes; (void)n_in; (void)out_size; (void)d_ws; (void)ws_size;

    const int grid = BB * CC;                    // 1024 blocks: one (b,c) plane each
    approx_dconv_kernel<<<grid, NTH, 0, stream>>>(x, w, lut, out);
}